// Round 5
// baseline (178.227 us; speedup 1.0000x reference)
//
#include <hip/hip_runtime.h>

// LRF kernel: per-batch 3x3 SVD emulating fp32 LAPACK sgesdd bit-path
// (gebd2 + bdsqr + ormbr). R5:
//  - einsum reduction now matches numpy's baseline-SSE kernel exactly:
//    vaccum threads through the per-16-block muladd chain (no FMA), SSE3
//    hadd tree at the end.
//  - Fortran-compiled LAPACK parts emulated with gfortran -ffp-contract=fast
//    codegen: a*b+c*d -> fmaf(a,b, c*d) (first product fused), sqrt(fma(..)).
//  - BLAS kernels (gemv/ger/axpy/rot, OpenBLAS Zen) keep FMA form.

#define DEVFN static __device__ __forceinline__

// ---------------- LAPACK fp32 helpers, gfortran-contract rounding ----------

DEVFN float slapy2f(float x, float y) {
#pragma clang fp contract(off)
  float xa = fabsf(x), ya = fabsf(y);
  float w = fmaxf(xa, ya);
  float z = fminf(xa, ya);
  if (z == 0.0f) return w;
  float q = z / w;
  return w * sqrtf(fmaf(q, q, 1.0f));   // W*SQRT(ONE+(Z/W)**2), contracted
}

// OpenBLAS x86-64 snrm2: double/x87-extended accumulation path for tiny n.
DEVFN float snrm2_2f(float a, float b) {
  double da = (double)a, db = (double)b;
  return (float)sqrt(da * da + db * db);
}

// LAPACK 3.10+ slartg (f90), gfortran-contracted.
DEVFN void slartgf(float f, float g, float &cs, float &sn, float &r) {
#pragma clang fp contract(off)
  if (g == 0.0f) { cs = 1.0f; sn = 0.0f; r = f; return; }
  if (f == 0.0f) { cs = 0.0f; sn = copysignf(1.0f, g); r = fabsf(g); return; }
  float f1 = fabsf(f), g1 = fabsf(g);
  const float rtmin = 0x1p-63f;
  const float rtmax = 6.5219089e18f;  // sqrt(safmax/2) = 2^62.5
  if (f1 > rtmin && f1 < rtmax && g1 > rtmin && g1 < rtmax) {
    float d = sqrtf(fmaf(f, f, g * g));   // SQRT(F*F+G*G) contracted
    cs = f1 / d;
    r = copysignf(d, f);
    sn = g / r;
  } else {
    const float safmin = 0x1p-126f;
    const float safmax = 0x1p+126f;
    float u = fminf(safmax, fmaxf(safmin, fmaxf(f1, g1)));
    float fs = f / u, gs = g / u;
    float d = sqrtf(fmaf(fs, fs, gs * gs));
    cs = fabsf(fs) / d;
    r = copysignf(d, f);
    sn = gs / r;
    r = r * u;
  }
}

DEVFN void slas2f(float f, float g, float h, float &ssmin, float &ssmax) {
#pragma clang fp contract(off)
  float fa = fabsf(f), ga = fabsf(g), ha = fabsf(h);
  float fhmn = fminf(fa, ha), fhmx = fmaxf(fa, ha);
  if (fhmn == 0.0f) {
    ssmin = 0.0f;
    if (fhmx == 0.0f) {
      ssmax = ga;
    } else {
      float mx = fmaxf(fhmx, ga), mn = fminf(fhmx, ga);
      float q = mn / mx;
      ssmax = mx * sqrtf(fmaf(q, q, 1.0f));
    }
  } else {
    if (ga < fhmx) {
      float as = 1.0f + fhmn / fhmx;
      float at = (fhmx - fhmn) / fhmx;
      float qq = ga / fhmx;
      float au = qq * qq;
      float c = 2.0f / (sqrtf(fmaf(as, as, au)) + sqrtf(fmaf(at, at, au)));
      ssmin = fhmn * c;
      ssmax = fhmx / c;
    } else {
      float au = fhmx / ga;
      if (au == 0.0f) {
        ssmin = (fhmn * fhmx) / ga;
        ssmax = ga;
      } else {
        float as = 1.0f + fhmn / fhmx;
        float at = (fhmx - fhmn) / fhmx;
        float q1 = as * au, q2 = at * au;
        float c = 1.0f / (sqrtf(fmaf(q1, q1, 1.0f)) + sqrtf(fmaf(q2, q2, 1.0f)));
        ssmin = (fhmn * c) * au;
        ssmin = ssmin + ssmin;
        ssmax = ga / (c + c);
      }
    }
  }
}

DEVFN void slasv2f(float f, float g, float h, float &ssmin, float &ssmax,
                   float &snr, float &csr, float &snl, float &csl) {
#pragma clang fp contract(off)
  const float eps = 0x1p-24f;
  float ft = f, fa = fabsf(f), ht = h, ha = fabsf(h);
  int pmax = 1;
  bool swp = (ha > fa);
  if (swp) {
    pmax = 3;
    float tmp = ft; ft = ht; ht = tmp;
    tmp = fa; fa = ha; ha = tmp;
  }
  float gt = g, ga = fabsf(g);
  float clt = 0.0f, crt = 0.0f, slt = 0.0f, srt = 0.0f;
  if (ga == 0.0f) {
    ssmin = ha; ssmax = fa;
    clt = 1.0f; crt = 1.0f; slt = 0.0f; srt = 0.0f;
  } else {
    bool gasmal = true;
    if (ga > fa) {
      pmax = 2;
      if ((fa / ga) < eps) {
        gasmal = false;
        ssmax = ga;
        if (ha > 1.0f) ssmin = fa / (ga / ha);
        else ssmin = (fa / ga) * ha;
        clt = 1.0f; slt = ht / gt; srt = 1.0f; crt = ft / gt;
      }
    }
    if (gasmal) {
      float dd = fa - ha;
      float l;
      if (dd == fa) l = 1.0f;
      else l = dd / fa;
      float m = gt / ft;
      float t = 2.0f - l;
      // MM=M*M defined first -> fused into both adds (gfortran fma pass)
      float s = sqrtf(fmaf(m, m, t * t));
      float r;
      if (l == 0.0f) r = fabsf(m);
      else r = sqrtf(fmaf(m, m, l * l));
      float a = 0.5f * (s + r);
      ssmin = ha / a;
      ssmax = fa * a;
      float mm = m * m;
      if (mm == 0.0f) {
        if (l == 0.0f) t = copysignf(2.0f, ft) * copysignf(1.0f, gt);
        else t = gt / copysignf(dd, ft) + m / t;
      } else {
        t = (m / (s + t) + m / (r + l)) * (1.0f + a);
      }
      float l2 = sqrtf(fmaf(t, t, 4.0f));
      crt = 2.0f / l2;
      srt = t / l2;
      clt = fmaf(srt, m, crt) / a;   // (CRT+SRT*M)/A contracted
      slt = (ht / ft) * srt / a;
    }
  }
  if (swp) { csl = srt; snl = crt; csr = slt; snr = clt; }
  else { csl = clt; snl = slt; csr = crt; snr = srt; }
  float tsign = 0.0f;
  if (pmax == 1) tsign = copysignf(1.0f, csr) * copysignf(1.0f, csl) * copysignf(1.0f, f);
  if (pmax == 2) tsign = copysignf(1.0f, snr) * copysignf(1.0f, csl) * copysignf(1.0f, g);
  if (pmax == 3) tsign = copysignf(1.0f, snr) * copysignf(1.0f, snl) * copysignf(1.0f, h);
  ssmax = copysignf(ssmax, tsign);
  ssmin = copysignf(ssmin, tsign * copysignf(1.0f, f) * copysignf(1.0f, h));
}

// sgesdd jobz='A' path for symmetric 3x3: sgebd2(3.12 slarf1f) -> sbdsdc
// (n<=25: slasdq -> sbdsqr) -> sormbr('P','R','T') G1 on VT row 3.
static __device__ void svd3_vlast(float c00, float c01, float c02,
                                  float c11, float c12, float c22,
                                  float vout[3]) {
#pragma clang fp contract(off)
  float a11 = c00, a12 = c01, a13 = c02;
  float a21 = c01, a22 = c11, a23 = c12;
  float a31 = c02, a32 = c12, a33 = c22;
  float d1, d2, d3, e1, e2;
  float taup1 = 0.0f, g2 = 0.0f;

  // ---- sgebd2 (LAPACK 3.12, slarf1f; BLAS = OpenBLAS FMA kernels) ----
  { // H(1): annihilate a21,a31
    float xnorm = snrm2_2f(a21, a31);
    if (xnorm == 0.0f) {
      d1 = a11;
    } else {
      float beta = -copysignf(slapy2f(a11, xnorm), a11);
      float tauq1 = (beta - a11) / beta;
      float sc = 1.0f / (a11 - beta);
      float v2 = a21 * sc, v3 = a31 * sc;
      d1 = beta;
      // sgemv('T', rows2..3, beta=0) + saxpy(1, row1)
      float w2 = fmaf(a32, v3, a22 * v2);
      float w3 = fmaf(a33, v3, a23 * v2);
      w2 = w2 + a12;
      w3 = w3 + a13;
      // saxpy(-tau) on row 1
      a12 = fmaf(-tauq1, w2, a12);
      a13 = fmaf(-tauq1, w3, a13);
      // sger on rows 2..3
      float t2 = -tauq1 * w2;
      float t3 = -tauq1 * w3;
      a22 = fmaf(v2, t2, a22); a32 = fmaf(v3, t2, a32);
      a23 = fmaf(v2, t3, a23); a33 = fmaf(v3, t3, a33);
    }
  }
  { // G(1): annihilate a13
    float xnorm = fabsf(a13);
    if (xnorm == 0.0f) {
      e1 = a12;  // taup1 = 0
    } else {
      float beta = -copysignf(slapy2f(a12, xnorm), a12);
      taup1 = (beta - a12) / beta;
      g2 = a13 * (1.0f / (a12 - beta));
      e1 = beta;
      // sgemv('N', col3, beta=0) + saxpy(1, col2)
      float w2 = a23 * g2;
      float w3 = a33 * g2;
      w2 = w2 + a22;
      w3 = w3 + a32;
      // saxpy(-tau) on col 2
      a22 = fmaf(-taup1, w2, a22);
      a32 = fmaf(-taup1, w3, a32);
      // sger col 3: temp = -tau*g2
      float tg = -taup1 * g2;
      a23 = fmaf(w2, tg, a23);
      a33 = fmaf(w3, tg, a33);
    }
  }
  { // H(2): annihilate a32
    float xnorm = fabsf(a32);
    if (xnorm == 0.0f) {
      d2 = a22;
    } else {
      float beta = -copysignf(slapy2f(a22, xnorm), a22);
      float tauq2 = (beta - a22) / beta;
      float h3 = a32 * (1.0f / (a22 - beta));
      d2 = beta;
      float w = a33 * h3;
      w = w + a23;
      a23 = fmaf(-tauq2, w, a23);
      float tw = -tauq2 * w;
      a33 = fmaf(h3, tw, a33);
    }
  }
  e2 = a23;
  d3 = a33;

  // ---- sbdsqr ('U', n=3, VT tracked), gfortran-contracted ----
  float d[4] = {0.0f, d1, d2, d3};
  float e[3] = {0.0f, e1, e2};
  float vt[4][4];
  for (int i = 1; i <= 3; ++i)
    for (int j = 1; j <= 3; ++j)
      vt[i][j] = (i == j) ? 1.0f : 0.0f;

  const float eps = 0x1p-24f;
  const float unfl = 0x1p-126f;
  const float tol = 10.0f * eps;
  float thresh;
  {
    float sminoa = fabsf(d[1]);
    if (sminoa != 0.0f) {
      float mu = sminoa;
      for (int i = 2; i <= 3; ++i) {
        mu = fabsf(d[i]) * (mu / (mu + fabsf(e[i - 1])));
        sminoa = fminf(sminoa, mu);
        if (sminoa == 0.0f) break;
      }
    }
    sminoa = sminoa / sqrtf(3.0f);
    thresh = fmaxf(tol * sminoa, 6.0f * (3.0f * (3.0f * unfl)));
  }
  int mq = 3;
  int iterq = -1, iterdivn = 0;
  const int maxitdivn = 18;
  int oldll = -1, oldm = -1, idir = 0;
  float sminl = 0.0f;
  int guard = 0;

  while (true) {
    if (mq <= 1) break;
    if (++guard > 300) break;
    if (iterq >= 3) {
      iterq -= 3;
      iterdivn += 1;
      if (iterdivn >= maxitdivn) break;
    }
    float smax = fabsf(d[mq]);
    int ll = 0;
    bool split = false;
    for (int lll = 1; lll <= mq - 1; ++lll) {
      ll = mq - lll;
      float abss = fabsf(d[ll]);
      float abse = fabsf(e[ll]);
      if (abse <= thresh) { split = true; break; }
      smax = fmaxf(fmaxf(smax, abss), abse);
    }
    if (split) {
      e[ll] = 0.0f;
      if (ll == mq - 1) { mq -= 1; continue; }
    } else {
      ll = 0;
    }
    ll += 1;
    if (ll == mq - 1) {
      // 2x2 block: slasv2 + srot (BLAS, FMA form) on VT rows (mq-1, mq)
      float sigmn, sigmx, sinr, cosr, sinl, cosl;
      slasv2f(d[mq - 1], e[mq - 1], d[mq], sigmn, sigmx, sinr, cosr, sinl, cosl);
      d[mq - 1] = sigmx;
      e[mq - 1] = 0.0f;
      d[mq] = sigmn;
      for (int col = 1; col <= 3; ++col) {
        float xx = vt[mq - 1][col], yy = vt[mq][col];
        float st = fmaf(cosr, xx, sinr * yy);
        vt[mq][col] = fmaf(cosr, yy, -(sinr * xx));
        vt[mq - 1][col] = st;
      }
      mq -= 2;
      continue;
    }
    if (ll > oldm || mq < oldll)
      idir = (fabsf(d[ll]) >= fabsf(d[mq])) ? 1 : 2;
    bool back = false;
    if (idir == 1) {
      if (fabsf(e[mq - 1]) <= tol * fabsf(d[mq])) { e[mq - 1] = 0.0f; continue; }
      float mu = fabsf(d[ll]);
      sminl = mu;
      for (int lll = ll; lll <= mq - 1; ++lll) {
        if (fabsf(e[lll]) <= tol * mu) { e[lll] = 0.0f; back = true; break; }
        mu = fabsf(d[lll + 1]) * (mu / (mu + fabsf(e[lll])));
        sminl = fminf(sminl, mu);
      }
    } else {
      if (fabsf(e[ll]) <= tol * fabsf(d[ll])) { e[ll] = 0.0f; continue; }
      float mu = fabsf(d[mq]);
      sminl = mu;
      for (int lll = mq - 1; lll >= ll; --lll) {
        if (fabsf(e[lll]) <= tol * mu) { e[lll] = 0.0f; back = true; break; }
        mu = fabsf(d[lll]) * (mu / (mu + fabsf(e[lll])));
        sminl = fminf(sminl, mu);
      }
    }
    if (back) continue;
    oldll = ll;
    oldm = mq;
    float shift = 0.0f;
    if (!((3.0f * tol) * (sminl / smax) <= fmaxf(eps, 0.01f * tol))) {
      float sll, rdum;
      if (idir == 1) { sll = fabsf(d[ll]); slas2f(d[mq - 1], e[mq - 1], d[mq], shift, rdum); }
      else { sll = fabsf(d[mq]); slas2f(d[ll], e[ll], d[ll + 1], shift, rdum); }
      if (sll > 0.0f) {
        float q = shift / sll;
        if (q * q < eps) shift = 0.0f;
      }
    }
    iterq += mq - ll;
    float rc[2], rs[2];
    int nrot = mq - ll;
    if (shift == 0.0f) {
      if (idir == 1) {
        float cs = 1.0f, oldcs = 1.0f, sn = 0.0f, oldsn = 0.0f, rr = 0.0f;
        for (int i = ll; i <= mq - 1; ++i) {
          float fq = d[i] * cs;
          slartgf(fq, e[i], cs, sn, rr);
          if (i > ll) e[i - 1] = oldsn * rr;
          float f2 = oldcs * rr;
          float g2q = d[i + 1] * sn;
          slartgf(f2, g2q, oldcs, oldsn, d[i]);
          rc[i - ll] = cs;   // WORK(1..) -> VT ('F')
          rs[i - ll] = sn;
        }
        float h = d[mq] * cs;
        d[mq] = h * oldcs;
        e[mq - 1] = h * oldsn;
        for (int j = 0; j < nrot; ++j) {  // slasr 'L','V','F' (contracted)
          float ct = rc[j], st = rs[j];
          if (ct != 1.0f || st != 0.0f)
            for (int col = 1; col <= 3; ++col) {
              float tmp = vt[ll + j + 1][col];
              vt[ll + j + 1][col] = fmaf(ct, tmp, -(st * vt[ll + j][col]));
              vt[ll + j][col] = fmaf(st, tmp, ct * vt[ll + j][col]);
            }
        }
        if (fabsf(e[mq - 1]) <= thresh) e[mq - 1] = 0.0f;
      } else {
        float cs = 1.0f, oldcs = 1.0f, sn = 0.0f, oldsn = 0.0f, rr = 0.0f;
        for (int i = mq; i >= ll + 1; --i) {
          float fq = d[i] * cs;
          slartgf(fq, e[i - 1], cs, sn, rr);
          if (i < mq) e[i] = oldsn * rr;
          float f2 = oldcs * rr;
          float g2q = d[i - 1] * sn;
          slartgf(f2, g2q, oldcs, oldsn, d[i]);
          rc[i - ll - 1] = oldcs;   // WORK(NM12+..) = OLDCS -> VT ('B')
          rs[i - ll - 1] = -oldsn;  // WORK(NM13+..) = -OLDSN
        }
        float h = d[ll] * cs;
        d[ll] = h * oldcs;
        e[ll] = h * oldsn;
        for (int j = nrot - 1; j >= 0; --j) {  // slasr 'L','V','B'
          float ct = rc[j], st = rs[j];
          if (ct != 1.0f || st != 0.0f)
            for (int col = 1; col <= 3; ++col) {
              float tmp = vt[ll + j + 1][col];
              vt[ll + j + 1][col] = fmaf(ct, tmp, -(st * vt[ll + j][col]));
              vt[ll + j][col] = fmaf(st, tmp, ct * vt[ll + j][col]);
            }
        }
        if (fabsf(e[ll]) <= thresh) e[ll] = 0.0f;
      }
    } else {
      if (idir == 1) {
        float fq = (fabsf(d[ll]) - shift) * (copysignf(1.0f, d[ll]) + shift / d[ll]);
        float gq = e[ll];
        float cosr = 0, sinr = 0, cosl = 0, sinl = 0, rr = 0;
        for (int i = ll; i <= mq - 1; ++i) {
          slartgf(fq, gq, cosr, sinr, rr);
          if (i > ll) e[i - 1] = rr;
          fq = fmaf(cosr, d[i], sinr * e[i]);          // COSR*D+SINR*E
          e[i] = fmaf(cosr, e[i], -(sinr * d[i]));     // COSR*E-SINR*D
          gq = sinr * d[i + 1];
          d[i + 1] = cosr * d[i + 1];
          slartgf(fq, gq, cosl, sinl, rr);
          d[i] = rr;
          fq = fmaf(cosl, e[i], sinl * d[i + 1]);      // COSL*E+SINL*D
          d[i + 1] = fmaf(cosl, d[i + 1], -(sinl * e[i]));
          if (i < mq - 1) {
            gq = sinl * e[i + 1];
            e[i + 1] = cosl * e[i + 1];
          }
          rc[i - ll] = cosr;  // WORK(1..) -> VT ('F')
          rs[i - ll] = sinr;
        }
        e[mq - 1] = fq;
        for (int j = 0; j < nrot; ++j) {
          float ct = rc[j], st = rs[j];
          if (ct != 1.0f || st != 0.0f)
            for (int col = 1; col <= 3; ++col) {
              float tmp = vt[ll + j + 1][col];
              vt[ll + j + 1][col] = fmaf(ct, tmp, -(st * vt[ll + j][col]));
              vt[ll + j][col] = fmaf(st, tmp, ct * vt[ll + j][col]);
            }
        }
        if (fabsf(e[mq - 1]) <= thresh) e[mq - 1] = 0.0f;
      } else {
        float fq = (fabsf(d[mq]) - shift) * (copysignf(1.0f, d[mq]) + shift / d[mq]);
        float gq = e[mq - 1];
        float cosr = 0, sinr = 0, cosl = 0, sinl = 0, rr = 0;
        for (int i = mq; i >= ll + 1; --i) {
          slartgf(fq, gq, cosr, sinr, rr);
          if (i < mq) e[i] = rr;
          fq = fmaf(cosr, d[i], sinr * e[i - 1]);
          e[i - 1] = fmaf(cosr, e[i - 1], -(sinr * d[i]));
          gq = sinr * d[i - 1];
          d[i - 1] = cosr * d[i - 1];
          slartgf(fq, gq, cosl, sinl, rr);
          d[i] = rr;
          fq = fmaf(cosl, e[i - 1], sinl * d[i - 1]);
          d[i - 1] = fmaf(cosl, d[i - 1], -(sinl * e[i - 1]));
          if (i > ll + 1) {
            gq = sinl * e[i - 2];
            e[i - 2] = cosl * e[i - 2];
          }
          rc[i - ll - 1] = cosl;   // WORK(NM12+..) = COSL -> VT ('B')
          rs[i - ll - 1] = -sinl;  // WORK(NM13+..) = -SINL
        }
        e[ll] = fq;
        if (fabsf(e[ll]) <= thresh) e[ll] = 0.0f;
        for (int j = nrot - 1; j >= 0; --j) {
          float ct = rc[j], st = rs[j];
          if (ct != 1.0f || st != 0.0f)
            for (int col = 1; col <= 3; ++col) {
              float tmp = vt[ll + j + 1][col];
              vt[ll + j + 1][col] = fmaf(ct, tmp, -(st * vt[ll + j][col]));
              vt[ll + j][col] = fmaf(st, tmp, ct * vt[ll + j][col]);
            }
        }
      }
    }
  }
  // make singular values positive
  for (int i = 1; i <= 3; ++i) {
    if (d[i] < 0.0f) {
      d[i] = -d[i];
      for (int col = 1; col <= 3; ++col) vt[i][col] = -vt[i][col];
    }
  }
  // sort decreasing (sbdsqr selection, ties -> last index)
  for (int i = 1; i <= 2; ++i) {
    int isub = 1;
    float smin = d[1];
    for (int j = 2; j <= 4 - i; ++j) {
      if (d[j] <= smin) { isub = j; smin = d[j]; }
    }
    if (isub != 4 - i) {
      d[isub] = d[4 - i];
      d[4 - i] = smin;
      for (int col = 1; col <= 3; ++col) {
        float tsw = vt[isub][col];
        vt[isub][col] = vt[4 - i][col];
        vt[4 - i][col] = tsw;
      }
    }
  }
  // sormbr('P','R','T') via slarf1f (row 3 of VT only)
  float r1 = vt[3][1], r2 = vt[3][2], r3 = vt[3][3];
  if (taup1 != 0.0f) {
    float w = r3 * g2;            // gemv-N (beta=0)
    w = w + r2;                   // saxpy(1)
    r2 = fmaf(-taup1, w, r2);     // saxpy(-tau) on col 2
    float tg = -taup1 * g2;       // sger col 3
    r3 = fmaf(w, tg, r3);
  }
  vout[0] = r1;
  vout[1] = r2;
  vout[2] = r3;
}

// ------ numpy einsum baseline-SSE reduction, exact shape -------------------
// contig_contig_outstride0_two, vstep=4, no FMA. One vstepx4(=16) iteration:
//   ab3 = a3*b3 + vaccum; ab2 = a2*b2 + ab3; ab1 = a1*b1 + ab2;
//   vaccum = a0*b0 + ab1        (per lane l)
// Final: accum = hadd tree (l0+l1)+(l2+l3).
DEVFN void einsum_chain16(float acc[4], const float *a, const float *b) {
#pragma clang fp contract(off)
#pragma unroll
  for (int l = 0; l < 4; ++l) {
    float ab3 = a[12 + l] * b[12 + l] + acc[l];
    float ab2 = a[8 + l] * b[8 + l] + ab3;
    float ab1 = a[4 + l] * b[4 + l] + ab2;
    acc[l] = a[l] * b[l] + ab1;
  }
}

DEVFN float hadd4(const float a[4]) {
#pragma clang fp contract(off)
  return (a[0] + a[1]) + (a[2] + a[3]);
}

// ---------------------------- main kernel ----------------------------------

union F4 { float4 v; float f[4]; };

__global__ __launch_bounds__(256) void LRF_70695161692718_kernel(
    const float* __restrict__ xyz, const float* __restrict__ xyzg,
    const float* __restrict__ rl, float* __restrict__ out, int B) {
#pragma clang fp contract(off)
  int b = blockIdx.x * blockDim.x + threadIdx.x;
  if (b >= B) return;
  const float* Xg = xyzg + (size_t)b * 192;
  const float4* X0 = (const float4*)(Xg);
  const float4* X1 = (const float4*)(Xg + 64);
  const float4* X2 = (const float4*)(Xg + 128);
  float cx = xyz[3 * b + 0], cy = xyz[3 * b + 1], cz = xyz[3 * b + 2];
  float r = rl[b];

  // ---- pass 1: covariance via exact numpy-einsum chain reduction
  float v00[4] = {0,0,0,0}, v01[4] = {0,0,0,0}, v02[4] = {0,0,0,0};
  float v11[4] = {0,0,0,0}, v12[4] = {0,0,0,0}, v22[4] = {0,0,0,0};
  for (int Bk = 0; Bk < 4; ++Bk) {
    float x0[16], x1[16], x2[16];
#pragma unroll
    for (int k = 0; k < 4; ++k) {
      F4 g0, g1, g2v;
      g0.v = X0[4 * Bk + k]; g1.v = X1[4 * Bk + k]; g2v.v = X2[4 * Bk + k];
#pragma unroll
      for (int l = 0; l < 4; ++l) {
        x0[4 * k + l] = cx - g0.f[l];
        x1[4 * k + l] = cy - g1.f[l];
        x2[4 * k + l] = cz - g2v.f[l];
      }
    }
    einsum_chain16(v00, x0, x0);
    einsum_chain16(v01, x0, x1);
    einsum_chain16(v02, x0, x2);
    einsum_chain16(v11, x1, x1);
    einsum_chain16(v12, x1, x2);
    einsum_chain16(v22, x2, x2);
  }
  float a00 = hadd4(v00) / 64.0f;
  float a01 = hadd4(v01) / 64.0f;
  float a02 = hadd4(v02) / 64.0f;
  float a11c = hadd4(v11) / 64.0f;
  float a12c = hadd4(v12) / 64.0f;
  float a22c = hadd4(v22) / 64.0f;

  float v[3];
  svd3_vlast(a00, a01, a02, a11c, a12c, a22c, v);

  // ---- pass 2: center_proj counts; numpy stride0_contig_outcontig:
  // out = v0*x0; out = v1*x1 + out; out = v2*x2 + out (mul+add, no fma)
  int npos = 0, nneg = 0;
  for (int k = 0; k < 16; ++k) {
    F4 g0, g1, g2v;
    g0.v = X0[k]; g1.v = X1[k]; g2v.v = X2[k];
#pragma unroll
    for (int j = 0; j < 4; ++j) {
      float x0 = cx - g0.f[j];
      float x1 = cy - g1.f[j];
      float x2 = cz - g2v.f[j];
      float p = v[0] * x0;
      p = v[1] * x1 + p;
      p = v[2] * x2 + p;
      npos += (p > 0.001f) ? 1 : 0;
      nneg += (p < -0.001f) ? 1 : 0;
    }
  }
  int sum_ = npos - nneg;
  float sgn = (sum_ < 0) ? -1.0f : 1.0f;
  float zp0 = sgn * v[0], zp1 = sgn * v[1], zp2 = sgn * v[2];

  // ---- pass 3: vi_c via exact einsum chain reduction
  float vca[4] = {0,0,0,0}, vcb[4] = {0,0,0,0}, vcc[4] = {0,0,0,0};
  for (int Bk = 0; Bk < 4; ++Bk) {
    float w16[16], q0[16], q1[16], q2[16];
#pragma unroll
    for (int k = 0; k < 4; ++k) {
      F4 g0, g1, g2v;
      g0.v = X0[4 * Bk + k]; g1.v = X1[4 * Bk + k]; g2v.v = X2[4 * Bk + k];
#pragma unroll
      for (int l = 0; l < 4; ++l) {
        int c = 4 * k + l;
        float y0 = g0.f[l] - cx;
        float y1 = g1.f[l] - cy;
        float y2 = g2v.f[l] - cz;
        float nm = zp0 * y0;              // norm einsum: sequential mul+add
        nm = zp1 * y1 + nm;
        nm = zp2 * y2 + nm;
        q0[c] = y0 - zp0 * nm;            // vi (mul then sub, no fma)
        q1[c] = y1 - zp1 * nm;
        q2[c] = y2 - zp2 * nm;
        float ss = y0 * y0;               // sum over i: ((t0+t1)+t2)
        ss = ss + y1 * y1;
        ss = ss + y2 * y2;
        float xl2 = sqrtf(ss);
        float am = r - xl2;
        float alpha = am * am;
        float beta = nm * nm;
        w16[c] = alpha * beta;
      }
    }
    einsum_chain16(vca, w16, q0);
    einsum_chain16(vcb, w16, q1);
    einsum_chain16(vcc, w16, q2);
  }
  float vcx = hadd4(vca);
  float vcy = hadd4(vcb);
  float vcz = hadd4(vcc);
  float ss = vcx * vcx;
  ss = ss + vcy * vcy;
  ss = ss + vcz * vcz;
  float den = sqrtf(ss) + 1e-10f;
  float xp0 = vcx / den, xp1 = vcy / den, xp2 = vcz / den;
  // yp = cross(xp, zp): mul, mul, sub
  float yp0 = xp1 * zp2 - xp2 * zp1;
  float yp1 = xp2 * zp0 - xp0 * zp2;
  float yp2 = xp0 * zp1 - xp1 * zp0;

  // ---- pass 4: out[j][c] = sum_i lrf[i][j]*((xyz_group-xyz)/r)[i][c]
  float* O = out + (size_t)b * 192;
  float4* O0 = (float4*)(O);
  float4* O1 = (float4*)(O + 64);
  float4* O2 = (float4*)(O + 128);
  for (int k = 0; k < 16; ++k) {
    F4 g0, g1, g2v, o0, o1, o2;
    g0.v = X0[k]; g1.v = X1[k]; g2v.v = X2[k];
#pragma unroll
    for (int j = 0; j < 4; ++j) {
      float y0 = g0.f[j] - cx;
      float y1 = g1.f[j] - cy;
      float y2 = g2v.f[j] - cz;
      float p0 = y0 / r, p1 = y1 / r, p2 = y2 / r;
      float t0 = xp0 * p0; t0 = xp1 * p1 + t0; t0 = xp2 * p2 + t0;
      float t1 = yp0 * p0; t1 = yp1 * p1 + t1; t1 = yp2 * p2 + t1;
      float t2 = zp0 * p0; t2 = zp1 * p1 + t2; t2 = zp2 * p2 + t2;
      o0.f[j] = t0; o1.f[j] = t1; o2.f[j] = t2;
    }
    O0[k] = o0.v; O1[k] = o1.v; O2[k] = o2.v;
  }
}

extern "C" void kernel_launch(void* const* d_in, const int* in_sizes, int n_in,
                              void* d_out, int out_size, void* d_ws, size_t ws_size,
                              hipStream_t stream) {
  (void)n_in; (void)out_size; (void)d_ws; (void)ws_size;
  const float* xyz = (const float*)d_in[0];
  const float* xyzg = (const float*)d_in[1];
  const float* rl = (const float*)d_in[2];
  float* out = (float*)d_out;
  int B = in_sizes[2];  // r_lrf has one element per batch
  int threads = 256;
  int blocks = (B + threads - 1) / threads;
  LRF_70695161692718_kernel<<<blocks, threads, 0, stream>>>(xyz, xyzg, rl, out, B);
}

// Round 6
// 165.361 us; speedup vs baseline: 1.0778x; 1.0778x over previous
//
#include <hip/hip_runtime.h>

// LRF kernel, R6 (perf): 4 threads per batch. numpy's einsum kernel has 4
// independent SIMD accumulator lanes combined by one hadd tree, so the
// reduction splits bit-exactly across a thread quad: lane l owns columns
// c == l (mod 4), runs the identical descending muladd chain, and the quad
// combines via __shfl_xor in the exact (l0+l1)+(l2+l3) order (IEEE add is
// commutative bitwise). Each thread caches its 48 input floats in VGPRs, so
// xyz_group is read from HBM once instead of 4x. SVD runs redundantly in all
// 4 quad lanes (free under SIMT). Numerics identical to the R5 passing kernel.

#define DEVFN static __device__ __forceinline__

// ---------------- LAPACK fp32 helpers, gfortran-contract rounding ----------

DEVFN float slapy2f(float x, float y) {
#pragma clang fp contract(off)
  float xa = fabsf(x), ya = fabsf(y);
  float w = fmaxf(xa, ya);
  float z = fminf(xa, ya);
  if (z == 0.0f) return w;
  float q = z / w;
  return w * sqrtf(fmaf(q, q, 1.0f));
}

DEVFN float snrm2_2f(float a, float b) {
  double da = (double)a, db = (double)b;
  return (float)sqrt(da * da + db * db);
}

DEVFN void slartgf(float f, float g, float &cs, float &sn, float &r) {
#pragma clang fp contract(off)
  if (g == 0.0f) { cs = 1.0f; sn = 0.0f; r = f; return; }
  if (f == 0.0f) { cs = 0.0f; sn = copysignf(1.0f, g); r = fabsf(g); return; }
  float f1 = fabsf(f), g1 = fabsf(g);
  const float rtmin = 0x1p-63f;
  const float rtmax = 6.5219089e18f;
  if (f1 > rtmin && f1 < rtmax && g1 > rtmin && g1 < rtmax) {
    float d = sqrtf(fmaf(f, f, g * g));
    cs = f1 / d;
    r = copysignf(d, f);
    sn = g / r;
  } else {
    const float safmin = 0x1p-126f;
    const float safmax = 0x1p+126f;
    float u = fminf(safmax, fmaxf(safmin, fmaxf(f1, g1)));
    float fs = f / u, gs = g / u;
    float d = sqrtf(fmaf(fs, fs, gs * gs));
    cs = fabsf(fs) / d;
    r = copysignf(d, f);
    sn = gs / r;
    r = r * u;
  }
}

DEVFN void slas2f(float f, float g, float h, float &ssmin, float &ssmax) {
#pragma clang fp contract(off)
  float fa = fabsf(f), ga = fabsf(g), ha = fabsf(h);
  float fhmn = fminf(fa, ha), fhmx = fmaxf(fa, ha);
  if (fhmn == 0.0f) {
    ssmin = 0.0f;
    if (fhmx == 0.0f) {
      ssmax = ga;
    } else {
      float mx = fmaxf(fhmx, ga), mn = fminf(fhmx, ga);
      float q = mn / mx;
      ssmax = mx * sqrtf(fmaf(q, q, 1.0f));
    }
  } else {
    if (ga < fhmx) {
      float as = 1.0f + fhmn / fhmx;
      float at = (fhmx - fhmn) / fhmx;
      float qq = ga / fhmx;
      float au = qq * qq;
      float c = 2.0f / (sqrtf(fmaf(as, as, au)) + sqrtf(fmaf(at, at, au)));
      ssmin = fhmn * c;
      ssmax = fhmx / c;
    } else {
      float au = fhmx / ga;
      if (au == 0.0f) {
        ssmin = (fhmn * fhmx) / ga;
        ssmax = ga;
      } else {
        float as = 1.0f + fhmn / fhmx;
        float at = (fhmx - fhmn) / fhmx;
        float q1 = as * au, q2 = at * au;
        float c = 1.0f / (sqrtf(fmaf(q1, q1, 1.0f)) + sqrtf(fmaf(q2, q2, 1.0f)));
        ssmin = (fhmn * c) * au;
        ssmin = ssmin + ssmin;
        ssmax = ga / (c + c);
      }
    }
  }
}

DEVFN void slasv2f(float f, float g, float h, float &ssmin, float &ssmax,
                   float &snr, float &csr, float &snl, float &csl) {
#pragma clang fp contract(off)
  const float eps = 0x1p-24f;
  float ft = f, fa = fabsf(f), ht = h, ha = fabsf(h);
  int pmax = 1;
  bool swp = (ha > fa);
  if (swp) {
    pmax = 3;
    float tmp = ft; ft = ht; ht = tmp;
    tmp = fa; fa = ha; ha = tmp;
  }
  float gt = g, ga = fabsf(g);
  float clt = 0.0f, crt = 0.0f, slt = 0.0f, srt = 0.0f;
  if (ga == 0.0f) {
    ssmin = ha; ssmax = fa;
    clt = 1.0f; crt = 1.0f; slt = 0.0f; srt = 0.0f;
  } else {
    bool gasmal = true;
    if (ga > fa) {
      pmax = 2;
      if ((fa / ga) < eps) {
        gasmal = false;
        ssmax = ga;
        if (ha > 1.0f) ssmin = fa / (ga / ha);
        else ssmin = (fa / ga) * ha;
        clt = 1.0f; slt = ht / gt; srt = 1.0f; crt = ft / gt;
      }
    }
    if (gasmal) {
      float dd = fa - ha;
      float l;
      if (dd == fa) l = 1.0f;
      else l = dd / fa;
      float m = gt / ft;
      float t = 2.0f - l;
      float s = sqrtf(fmaf(m, m, t * t));
      float r;
      if (l == 0.0f) r = fabsf(m);
      else r = sqrtf(fmaf(m, m, l * l));
      float a = 0.5f * (s + r);
      ssmin = ha / a;
      ssmax = fa * a;
      float mm = m * m;
      if (mm == 0.0f) {
        if (l == 0.0f) t = copysignf(2.0f, ft) * copysignf(1.0f, gt);
        else t = gt / copysignf(dd, ft) + m / t;
      } else {
        t = (m / (s + t) + m / (r + l)) * (1.0f + a);
      }
      float l2 = sqrtf(fmaf(t, t, 4.0f));
      crt = 2.0f / l2;
      srt = t / l2;
      clt = fmaf(srt, m, crt) / a;
      slt = (ht / ft) * srt / a;
    }
  }
  if (swp) { csl = srt; snl = crt; csr = slt; snr = clt; }
  else { csl = clt; snl = slt; csr = crt; snr = srt; }
  float tsign = 0.0f;
  if (pmax == 1) tsign = copysignf(1.0f, csr) * copysignf(1.0f, csl) * copysignf(1.0f, f);
  if (pmax == 2) tsign = copysignf(1.0f, snr) * copysignf(1.0f, csl) * copysignf(1.0f, g);
  if (pmax == 3) tsign = copysignf(1.0f, snr) * copysignf(1.0f, snl) * copysignf(1.0f, h);
  ssmax = copysignf(ssmax, tsign);
  ssmin = copysignf(ssmin, tsign * copysignf(1.0f, f) * copysignf(1.0f, h));
}

// sgesdd jobz='A' path for symmetric 3x3 (unchanged from R5 passing kernel).
static __device__ void svd3_vlast(float c00, float c01, float c02,
                                  float c11, float c12, float c22,
                                  float vout[3]) {
#pragma clang fp contract(off)
  float a11 = c00, a12 = c01, a13 = c02;
  float a21 = c01, a22 = c11, a23 = c12;
  float a31 = c02, a32 = c12, a33 = c22;
  float d1, d2, d3, e1, e2;
  float taup1 = 0.0f, g2 = 0.0f;

  { // H(1)
    float xnorm = snrm2_2f(a21, a31);
    if (xnorm == 0.0f) {
      d1 = a11;
    } else {
      float beta = -copysignf(slapy2f(a11, xnorm), a11);
      float tauq1 = (beta - a11) / beta;
      float sc = 1.0f / (a11 - beta);
      float v2 = a21 * sc, v3 = a31 * sc;
      d1 = beta;
      float w2 = fmaf(a32, v3, a22 * v2);
      float w3 = fmaf(a33, v3, a23 * v2);
      w2 = w2 + a12;
      w3 = w3 + a13;
      a12 = fmaf(-tauq1, w2, a12);
      a13 = fmaf(-tauq1, w3, a13);
      float t2 = -tauq1 * w2;
      float t3 = -tauq1 * w3;
      a22 = fmaf(v2, t2, a22); a32 = fmaf(v3, t2, a32);
      a23 = fmaf(v2, t3, a23); a33 = fmaf(v3, t3, a33);
    }
  }
  { // G(1)
    float xnorm = fabsf(a13);
    if (xnorm == 0.0f) {
      e1 = a12;
    } else {
      float beta = -copysignf(slapy2f(a12, xnorm), a12);
      taup1 = (beta - a12) / beta;
      g2 = a13 * (1.0f / (a12 - beta));
      e1 = beta;
      float w2 = a23 * g2;
      float w3 = a33 * g2;
      w2 = w2 + a22;
      w3 = w3 + a32;
      a22 = fmaf(-taup1, w2, a22);
      a32 = fmaf(-taup1, w3, a32);
      float tg = -taup1 * g2;
      a23 = fmaf(w2, tg, a23);
      a33 = fmaf(w3, tg, a33);
    }
  }
  { // H(2)
    float xnorm = fabsf(a32);
    if (xnorm == 0.0f) {
      d2 = a22;
    } else {
      float beta = -copysignf(slapy2f(a22, xnorm), a22);
      float tauq2 = (beta - a22) / beta;
      float h3 = a32 * (1.0f / (a22 - beta));
      d2 = beta;
      float w = a33 * h3;
      w = w + a23;
      a23 = fmaf(-tauq2, w, a23);
      float tw = -tauq2 * w;
      a33 = fmaf(h3, tw, a33);
    }
  }
  e2 = a23;
  d3 = a33;

  float d[4] = {0.0f, d1, d2, d3};
  float e[3] = {0.0f, e1, e2};
  float vt[4][4];
  for (int i = 1; i <= 3; ++i)
    for (int j = 1; j <= 3; ++j)
      vt[i][j] = (i == j) ? 1.0f : 0.0f;

  const float eps = 0x1p-24f;
  const float unfl = 0x1p-126f;
  const float tol = 10.0f * eps;
  float thresh;
  {
    float sminoa = fabsf(d[1]);
    if (sminoa != 0.0f) {
      float mu = sminoa;
      for (int i = 2; i <= 3; ++i) {
        mu = fabsf(d[i]) * (mu / (mu + fabsf(e[i - 1])));
        sminoa = fminf(sminoa, mu);
        if (sminoa == 0.0f) break;
      }
    }
    sminoa = sminoa / sqrtf(3.0f);
    thresh = fmaxf(tol * sminoa, 6.0f * (3.0f * (3.0f * unfl)));
  }
  int mq = 3;
  int iterq = -1, iterdivn = 0;
  const int maxitdivn = 18;
  int oldll = -1, oldm = -1, idir = 0;
  float sminl = 0.0f;
  int guard = 0;

  while (true) {
    if (mq <= 1) break;
    if (++guard > 300) break;
    if (iterq >= 3) {
      iterq -= 3;
      iterdivn += 1;
      if (iterdivn >= maxitdivn) break;
    }
    float smax = fabsf(d[mq]);
    int ll = 0;
    bool split = false;
    for (int lll = 1; lll <= mq - 1; ++lll) {
      ll = mq - lll;
      float abss = fabsf(d[ll]);
      float abse = fabsf(e[ll]);
      if (abse <= thresh) { split = true; break; }
      smax = fmaxf(fmaxf(smax, abss), abse);
    }
    if (split) {
      e[ll] = 0.0f;
      if (ll == mq - 1) { mq -= 1; continue; }
    } else {
      ll = 0;
    }
    ll += 1;
    if (ll == mq - 1) {
      float sigmn, sigmx, sinr, cosr, sinl, cosl;
      slasv2f(d[mq - 1], e[mq - 1], d[mq], sigmn, sigmx, sinr, cosr, sinl, cosl);
      d[mq - 1] = sigmx;
      e[mq - 1] = 0.0f;
      d[mq] = sigmn;
      for (int col = 1; col <= 3; ++col) {
        float xx = vt[mq - 1][col], yy = vt[mq][col];
        float st = fmaf(cosr, xx, sinr * yy);
        vt[mq][col] = fmaf(cosr, yy, -(sinr * xx));
        vt[mq - 1][col] = st;
      }
      mq -= 2;
      continue;
    }
    if (ll > oldm || mq < oldll)
      idir = (fabsf(d[ll]) >= fabsf(d[mq])) ? 1 : 2;
    bool back = false;
    if (idir == 1) {
      if (fabsf(e[mq - 1]) <= tol * fabsf(d[mq])) { e[mq - 1] = 0.0f; continue; }
      float mu = fabsf(d[ll]);
      sminl = mu;
      for (int lll = ll; lll <= mq - 1; ++lll) {
        if (fabsf(e[lll]) <= tol * mu) { e[lll] = 0.0f; back = true; break; }
        mu = fabsf(d[lll + 1]) * (mu / (mu + fabsf(e[lll])));
        sminl = fminf(sminl, mu);
      }
    } else {
      if (fabsf(e[ll]) <= tol * fabsf(d[ll])) { e[ll] = 0.0f; continue; }
      float mu = fabsf(d[mq]);
      sminl = mu;
      for (int lll = mq - 1; lll >= ll; --lll) {
        if (fabsf(e[lll]) <= tol * mu) { e[lll] = 0.0f; back = true; break; }
        mu = fabsf(d[lll]) * (mu / (mu + fabsf(e[lll])));
        sminl = fminf(sminl, mu);
      }
    }
    if (back) continue;
    oldll = ll;
    oldm = mq;
    float shift = 0.0f;
    if (!((3.0f * tol) * (sminl / smax) <= fmaxf(eps, 0.01f * tol))) {
      float sll, rdum;
      if (idir == 1) { sll = fabsf(d[ll]); slas2f(d[mq - 1], e[mq - 1], d[mq], shift, rdum); }
      else { sll = fabsf(d[mq]); slas2f(d[ll], e[ll], d[ll + 1], shift, rdum); }
      if (sll > 0.0f) {
        float q = shift / sll;
        if (q * q < eps) shift = 0.0f;
      }
    }
    iterq += mq - ll;
    float rc[2], rs[2];
    int nrot = mq - ll;
    if (shift == 0.0f) {
      if (idir == 1) {
        float cs = 1.0f, oldcs = 1.0f, sn = 0.0f, oldsn = 0.0f, rr = 0.0f;
        for (int i = ll; i <= mq - 1; ++i) {
          float fq = d[i] * cs;
          slartgf(fq, e[i], cs, sn, rr);
          if (i > ll) e[i - 1] = oldsn * rr;
          float f2 = oldcs * rr;
          float g2q = d[i + 1] * sn;
          slartgf(f2, g2q, oldcs, oldsn, d[i]);
          rc[i - ll] = cs;
          rs[i - ll] = sn;
        }
        float h = d[mq] * cs;
        d[mq] = h * oldcs;
        e[mq - 1] = h * oldsn;
        for (int j = 0; j < nrot; ++j) {
          float ct = rc[j], st = rs[j];
          if (ct != 1.0f || st != 0.0f)
            for (int col = 1; col <= 3; ++col) {
              float tmp = vt[ll + j + 1][col];
              vt[ll + j + 1][col] = fmaf(ct, tmp, -(st * vt[ll + j][col]));
              vt[ll + j][col] = fmaf(st, tmp, ct * vt[ll + j][col]);
            }
        }
        if (fabsf(e[mq - 1]) <= thresh) e[mq - 1] = 0.0f;
      } else {
        float cs = 1.0f, oldcs = 1.0f, sn = 0.0f, oldsn = 0.0f, rr = 0.0f;
        for (int i = mq; i >= ll + 1; --i) {
          float fq = d[i] * cs;
          slartgf(fq, e[i - 1], cs, sn, rr);
          if (i < mq) e[i] = oldsn * rr;
          float f2 = oldcs * rr;
          float g2q = d[i - 1] * sn;
          slartgf(f2, g2q, oldcs, oldsn, d[i]);
          rc[i - ll - 1] = oldcs;
          rs[i - ll - 1] = -oldsn;
        }
        float h = d[ll] * cs;
        d[ll] = h * oldcs;
        e[ll] = h * oldsn;
        for (int j = nrot - 1; j >= 0; --j) {
          float ct = rc[j], st = rs[j];
          if (ct != 1.0f || st != 0.0f)
            for (int col = 1; col <= 3; ++col) {
              float tmp = vt[ll + j + 1][col];
              vt[ll + j + 1][col] = fmaf(ct, tmp, -(st * vt[ll + j][col]));
              vt[ll + j][col] = fmaf(st, tmp, ct * vt[ll + j][col]);
            }
        }
        if (fabsf(e[ll]) <= thresh) e[ll] = 0.0f;
      }
    } else {
      if (idir == 1) {
        float fq = (fabsf(d[ll]) - shift) * (copysignf(1.0f, d[ll]) + shift / d[ll]);
        float gq = e[ll];
        float cosr = 0, sinr = 0, cosl = 0, sinl = 0, rr = 0;
        for (int i = ll; i <= mq - 1; ++i) {
          slartgf(fq, gq, cosr, sinr, rr);
          if (i > ll) e[i - 1] = rr;
          fq = fmaf(cosr, d[i], sinr * e[i]);
          e[i] = fmaf(cosr, e[i], -(sinr * d[i]));
          gq = sinr * d[i + 1];
          d[i + 1] = cosr * d[i + 1];
          slartgf(fq, gq, cosl, sinl, rr);
          d[i] = rr;
          fq = fmaf(cosl, e[i], sinl * d[i + 1]);
          d[i + 1] = fmaf(cosl, d[i + 1], -(sinl * e[i]));
          if (i < mq - 1) {
            gq = sinl * e[i + 1];
            e[i + 1] = cosl * e[i + 1];
          }
          rc[i - ll] = cosr;
          rs[i - ll] = sinr;
        }
        e[mq - 1] = fq;
        for (int j = 0; j < nrot; ++j) {
          float ct = rc[j], st = rs[j];
          if (ct != 1.0f || st != 0.0f)
            for (int col = 1; col <= 3; ++col) {
              float tmp = vt[ll + j + 1][col];
              vt[ll + j + 1][col] = fmaf(ct, tmp, -(st * vt[ll + j][col]));
              vt[ll + j][col] = fmaf(st, tmp, ct * vt[ll + j][col]);
            }
        }
        if (fabsf(e[mq - 1]) <= thresh) e[mq - 1] = 0.0f;
      } else {
        float fq = (fabsf(d[mq]) - shift) * (copysignf(1.0f, d[mq]) + shift / d[mq]);
        float gq = e[mq - 1];
        float cosr = 0, sinr = 0, cosl = 0, sinl = 0, rr = 0;
        for (int i = mq; i >= ll + 1; --i) {
          slartgf(fq, gq, cosr, sinr, rr);
          if (i < mq) e[i] = rr;
          fq = fmaf(cosr, d[i], sinr * e[i - 1]);
          e[i - 1] = fmaf(cosr, e[i - 1], -(sinr * d[i]));
          gq = sinr * d[i - 1];
          d[i - 1] = cosr * d[i - 1];
          slartgf(fq, gq, cosl, sinl, rr);
          d[i] = rr;
          fq = fmaf(cosl, e[i - 1], sinl * d[i - 1]);
          d[i - 1] = fmaf(cosl, d[i - 1], -(sinl * e[i - 1]));
          if (i > ll + 1) {
            gq = sinl * e[i - 2];
            e[i - 2] = cosl * e[i - 2];
          }
          rc[i - ll - 1] = cosl;
          rs[i - ll - 1] = -sinl;
        }
        e[ll] = fq;
        if (fabsf(e[ll]) <= thresh) e[ll] = 0.0f;
        for (int j = nrot - 1; j >= 0; --j) {
          float ct = rc[j], st = rs[j];
          if (ct != 1.0f || st != 0.0f)
            for (int col = 1; col <= 3; ++col) {
              float tmp = vt[ll + j + 1][col];
              vt[ll + j + 1][col] = fmaf(ct, tmp, -(st * vt[ll + j][col]));
              vt[ll + j][col] = fmaf(st, tmp, ct * vt[ll + j][col]);
            }
        }
      }
    }
  }
  for (int i = 1; i <= 3; ++i) {
    if (d[i] < 0.0f) {
      d[i] = -d[i];
      for (int col = 1; col <= 3; ++col) vt[i][col] = -vt[i][col];
    }
  }
  for (int i = 1; i <= 2; ++i) {
    int isub = 1;
    float smin = d[1];
    for (int j = 2; j <= 4 - i; ++j) {
      if (d[j] <= smin) { isub = j; smin = d[j]; }
    }
    if (isub != 4 - i) {
      d[isub] = d[4 - i];
      d[4 - i] = smin;
      for (int col = 1; col <= 3; ++col) {
        float tsw = vt[isub][col];
        vt[isub][col] = vt[4 - i][col];
        vt[4 - i][col] = tsw;
      }
    }
  }
  float r1 = vt[3][1], r2 = vt[3][2], r3 = vt[3][3];
  if (taup1 != 0.0f) {
    float w = r3 * g2;
    w = w + r2;
    r2 = fmaf(-taup1, w, r2);
    float tg = -taup1 * g2;
    r3 = fmaf(w, tg, r3);
  }
  vout[0] = r1;
  vout[1] = r2;
  vout[2] = r3;
}

// Quad hadd: (l0+l1)+(l2+l3), bit-identical in all 4 lanes of the quad
// (IEEE addition is commutative bitwise, so the xor pairing is exact).
DEVFN float qsum(float x) {
#pragma clang fp contract(off)
  float s = x + __shfl_xor(x, 1);
  return s + __shfl_xor(s, 2);
}
DEVFN int qsumi(int x) {
  int s = x + __shfl_xor(x, 1);
  return s + __shfl_xor(s, 2);
}

// One einsum vaccum-chain step for this lane's 4 elements of a 16-block,
// descending j (matches ab3->ab2->ab1->vaccum order). No FMA.
#define CHAIN4(acc, A, Bv)            \
  do {                                \
    float t_ = A[3] * Bv[3] + acc;    \
    t_ = A[2] * Bv[2] + t_;           \
    t_ = A[1] * Bv[1] + t_;           \
    acc = A[0] * Bv[0] + t_;          \
  } while (0)

// ---------------------------- main kernel ----------------------------------

__global__ __launch_bounds__(256) void LRF_70695161692718_kernel(
    const float* __restrict__ xyz, const float* __restrict__ xyzg,
    const float* __restrict__ rl, float* __restrict__ out, int B) {
#pragma clang fp contract(off)
  int tid = blockIdx.x * blockDim.x + threadIdx.x;
  int b = tid >> 2;        // batch
  int l = tid & 3;         // einsum SIMD lane (column class c % 4 == l)
  if (b >= B) return;
  const float* Xg = xyzg + (size_t)b * 192;
  float cx = xyz[3 * b + 0], cy = xyz[3 * b + 1], cz = xyz[3 * b + 2];
  float r = rl[b];

  // Load this lane's 48 floats once into VGPRs: columns c = 4*i + l.
  float r0[16], r1[16], r2[16];
#pragma unroll
  for (int i = 0; i < 16; ++i) {
    int col = 4 * i + l;
    r0[i] = Xg[col];
    r1[i] = Xg[64 + col];
    r2[i] = Xg[128 + col];
  }

  // ---- pass 1: covariance (exact einsum chain per lane + quad hadd)
  float a00 = 0, a01 = 0, a02 = 0, a11 = 0, a12 = 0, a22 = 0;
#pragma unroll
  for (int Bk = 0; Bk < 4; ++Bk) {
    float x0[4], x1[4], x2[4];
#pragma unroll
    for (int j = 0; j < 4; ++j) {
      int i = 4 * Bk + j;
      x0[j] = cx - r0[i];
      x1[j] = cy - r1[i];
      x2[j] = cz - r2[i];
    }
    CHAIN4(a00, x0, x0);
    CHAIN4(a01, x0, x1);
    CHAIN4(a02, x0, x2);
    CHAIN4(a11, x1, x1);
    CHAIN4(a12, x1, x2);
    CHAIN4(a22, x2, x2);
  }
  a00 = qsum(a00) / 64.0f;
  a01 = qsum(a01) / 64.0f;
  a02 = qsum(a02) / 64.0f;
  a11 = qsum(a11) / 64.0f;
  a12 = qsum(a12) / 64.0f;
  a22 = qsum(a22) / 64.0f;

  float v[3];
  svd3_vlast(a00, a01, a02, a11, a12, a22, v);  // redundant across quad: free

  // ---- pass 2: center_proj counts (integer, order-free across quad)
  int npos = 0, nneg = 0;
#pragma unroll
  for (int i = 0; i < 16; ++i) {
    float x0 = cx - r0[i];
    float x1 = cy - r1[i];
    float x2 = cz - r2[i];
    float p = v[0] * x0;
    p = v[1] * x1 + p;
    p = v[2] * x2 + p;
    npos += (p > 0.001f) ? 1 : 0;
    nneg += (p < -0.001f) ? 1 : 0;
  }
  int sum_ = qsumi(npos) - qsumi(nneg);
  float sgn = (sum_ < 0) ? -1.0f : 1.0f;
  float zp0 = sgn * v[0], zp1 = sgn * v[1], zp2 = sgn * v[2];

  // ---- pass 3: vi_c (exact einsum chain per lane + quad hadd)
  float vx = 0, vy = 0, vz = 0;
#pragma unroll
  for (int Bk = 0; Bk < 4; ++Bk) {
    float w[4], q0[4], q1[4], q2[4];
#pragma unroll
    for (int j = 0; j < 4; ++j) {
      int i = 4 * Bk + j;
      float y0 = r0[i] - cx;
      float y1 = r1[i] - cy;
      float y2 = r2[i] - cz;
      float nm = zp0 * y0;
      nm = zp1 * y1 + nm;
      nm = zp2 * y2 + nm;
      q0[j] = y0 - zp0 * nm;
      q1[j] = y1 - zp1 * nm;
      q2[j] = y2 - zp2 * nm;
      float ss = y0 * y0;
      ss = ss + y1 * y1;
      ss = ss + y2 * y2;
      float xl2 = sqrtf(ss);
      float am = r - xl2;
      float alpha = am * am;
      float beta = nm * nm;
      w[j] = alpha * beta;
    }
    CHAIN4(vx, w, q0);
    CHAIN4(vy, w, q1);
    CHAIN4(vz, w, q2);
  }
  float vcx = qsum(vx);
  float vcy = qsum(vy);
  float vcz = qsum(vz);
  float ss = vcx * vcx;
  ss = ss + vcy * vcy;
  ss = ss + vcz * vcz;
  float den = sqrtf(ss) + 1e-10f;
  float xp0 = vcx / den, xp1 = vcy / den, xp2 = vcz / den;
  float yp0 = xp1 * zp2 - xp2 * zp1;
  float yp1 = xp2 * zp0 - xp0 * zp2;
  float yp2 = xp0 * zp1 - xp1 * zp0;

  // ---- pass 4: rotate and write this lane's 16 columns
  float* O = out + (size_t)b * 192;
#pragma unroll
  for (int i = 0; i < 16; ++i) {
    int col = 4 * i + l;
    float y0 = r0[i] - cx;
    float y1 = r1[i] - cy;
    float y2 = r2[i] - cz;
    float p0 = y0 / r, p1 = y1 / r, p2 = y2 / r;
    float t0 = xp0 * p0; t0 = xp1 * p1 + t0; t0 = xp2 * p2 + t0;
    float t1 = yp0 * p0; t1 = yp1 * p1 + t1; t1 = yp2 * p2 + t1;
    float t2 = zp0 * p0; t2 = zp1 * p1 + t2; t2 = zp2 * p2 + t2;
    O[col] = t0;
    O[64 + col] = t1;
    O[128 + col] = t2;
  }
}

extern "C" void kernel_launch(void* const* d_in, const int* in_sizes, int n_in,
                              void* d_out, int out_size, void* d_ws, size_t ws_size,
                              hipStream_t stream) {
  (void)n_in; (void)out_size; (void)d_ws; (void)ws_size;
  const float* xyz = (const float*)d_in[0];
  const float* xyzg = (const float*)d_in[1];
  const float* rl = (const float*)d_in[2];
  float* out = (float*)d_out;
  int B = in_sizes[2];  // r_lrf has one element per batch
  int threads = 256;
  int blocks = (B * 4 + threads - 1) / threads;
  LRF_70695161692718_kernel<<<blocks, threads, 0, stream>>>(xyz, xyzg, rl, out, B);
}